// Round 9
// baseline (409.167 us; speedup 1.0000x reference)
//
#include <hip/hip_runtime.h>
#include <hip/hip_bf16.h>

#define DGRID 128
#define E1 127
#define E2 125
#define E3 123

typedef __attribute__((ext_vector_type(8))) short short8;
typedef __attribute__((ext_vector_type(4))) float f32x4;

static __device__ __forceinline__ unsigned short f2bf(float f) {
    union { __hip_bfloat16 h; unsigned short u; } cv;
    cv.h = __float2bfloat16(f);
    return cv.u;
}

// conv12 x1-row swizzle: row = 20 slots * 32B = 640B, XOR bits[4:6] by (x>>2).
static __device__ __forceinline__ int swz(int x, int h) {
    int off = x * 32 + h * 16;
    return off ^ (((x >> 2) & 7) << 4);
}

// conv3 x2-record offset: row padded to 24 slots * 16B = 384B; XOR bits[4:6] by (row&7).
static __device__ __forceinline__ int r3off(int row, int x) {
    return row * 384 + ((x * 16) ^ ((row & 7) << 4));
}

// ---------------- stage 0: zero dense grid (4-ch padded) ----------------
__global__ __launch_bounds__(256) void zero_k(float4* __restrict__ p, int n4) {
    int i = blockIdx.x * 256 + threadIdx.x;
    if (i < n4) p[i] = make_float4(0.f, 0.f, 0.f, 0.f);
}

// ---------------- stage 1: scatter voxels into dense grid ----------------
__global__ __launch_bounds__(256) void scatter_k(const int* __restrict__ coords,
                                                 const float* __restrict__ voxels,
                                                 float* __restrict__ dense, int N) {
    int i = blockIdx.x * blockDim.x + threadIdx.x;
    if (i >= N * 3) return;
    int n = i / 3, c = i - n * 3;
    int b = coords[n * 4 + 0];
    int z = coords[n * 4 + 1];
    int y = coords[n * 4 + 2];
    int x = coords[n * 4 + 3];
    int idx = (((b * DGRID + z) * DGRID + y) * DGRID + x) * 4 + c;   // 4-ch padded
    atomicAdd(&dense[idx], voxels[n * 3 + c]);
}

// ---------------- stage 2: fused conv1 (fp32 VALU) + conv2 (bf16 MFMA) ----------------
// Block: 256 threads (4 waves). Output tile (z8, y8, x16) of x2.
// Phase 1: x1 tile [10z][10y][18x] fp32 -> bf16 into swizzled LDS; rr loop FULLY unrolled
//          so 8 float4 loads are in flight per position (MLP fix for r8's stall).
// Phase 2: implicit GEMM, 14 x mfma_16x16x32_bf16 per 16 outputs; weights in 56 VGPRs.
// Epilogue: x2 written as bf16 8-ch records (16B); cols 5..7 are exact 0 (B-frag zero).
__global__ __launch_bounds__(256, 2) void conv12_k(const float* __restrict__ dense,
                                                   const float* __restrict__ W1f,
                                                   const float* __restrict__ W2f,
                                                   short* __restrict__ x2s) {
    __shared__ __align__(16) char sX1[64000];   // 10z * 10y rows * 640B

    const int tid = threadIdx.x;
    int blk = blockIdx.x;
    const int xt  = blk & 7;  blk >>= 3;
    const int tyt = blk & 15; blk >>= 4;
    const int tzt = blk & 15; blk >>= 4;
    const int b   = blk;
    const int z0 = tzt * 8, y0 = tyt * 8, x0 = xt * 16;

    // ---- phase 1: conv1. p = rep*256 + tid -> lanes cover consecutive x.
#pragma unroll 1
    for (int rep = 0; rep < 8; ++rep) {
        const int p = rep * 256 + tid;
        if (p < 1800) {
            const int xs = p % 18;
            const int ys = (p / 18) % 10;
            const int zs = p / 180;

            const int dxa = min(x0 + xs, DGRID - 1);
            const int dxb = min(x0 + xs + 1, DGRID - 1);

            // issue all 8 row loads together (full unroll -> 8 outstanding float4)
            float4 va[4], vb[4];
#pragma unroll
            for (int rr = 0; rr < 4; ++rr) {
                const int kz = rr >> 1, ky = rr & 1;
                const int dz = min(z0 + zs + kz, DGRID - 1);
                const int dy = min(y0 + ys + ky, DGRID - 1);
                const size_t rowbase = (size_t)((b * DGRID + dz) * DGRID + dy) * DGRID;
                va[rr] = *(const float4*)(dense + (rowbase + dxa) * 4);
                vb[rr] = *(const float4*)(dense + (rowbase + dxb) * 4);
            }

            float acc[9];
#pragma unroll
            for (int o = 0; o < 9; ++o) acc[o] = 0.f;
#pragma unroll
            for (int rr = 0; rr < 4; ++rr) {
                const int kz = rr >> 1, ky = rr & 1;
                const float* w0 = W1f + ((kz * 2 + ky) * 2 + 0) * 27;  // kx=0 tap
                const float* w1 = W1f + ((kz * 2 + ky) * 2 + 1) * 27;  // kx=1 tap
#pragma unroll
                for (int o = 0; o < 9; ++o)
                    acc[o] += va[rr].x * w0[o] + va[rr].y * w0[9 + o] + va[rr].z * w0[18 + o] +
                              vb[rr].x * w1[o] + vb[rr].y * w1[9 + o] + vb[rr].z * w1[18 + o];
            }
            const int R = (zs * 10 + ys) * 640;
            short8 lo, hi;
#pragma unroll
            for (int o = 0; o < 8; ++o) lo[o] = (short)f2bf(acc[o]);
            hi[0] = (short)f2bf(acc[8]);
#pragma unroll
            for (int o = 1; o < 8; ++o) hi[o] = 0;
            *(short8*)(sX1 + R + swz(xs, 0)) = lo;
            *(short8*)(sX1 + R + swz(xs, 1)) = hi;
        }
    }

    // ---- conv2 B-fragments: k' = tap*16+ci, col = out-ch; lane: col=lane&15, k'=32t+(lane>>4)*8+j
    const int lane = tid & 63;
    const int col  = lane & 15;
    const int q4   = lane >> 4;          // 0..3
    short8 B2[14];
#pragma unroll
    for (int t = 0; t < 14; ++t) {
#pragma unroll
        for (int j = 0; j < 8; ++j) {
            const int kp = t * 32 + q4 * 8 + j;
            const int tap = kp >> 4, ci = kp & 15;
            float v = 0.f;
            if (tap < 27 && ci < 9 && col < 5) v = W2f[(tap * 9 + ci) * 5 + col];
            B2[t][j] = (short)f2bf(v);
        }
    }
    __syncthreads();

    // ---- phase 2: conv2 via MFMA. Groups g = (z'<<3)|y', 64 groups / 4 waves.
    const int wv = tid >> 6;
    const int s  = q4 >> 1;              // tap-parity selector
    const int h  = q4 & 1;               // 16B-half (ci 0-7 / 8-15)
#pragma unroll 1
    for (int gi = 0; gi < 16; ++gi) {
        const int g = wv * 16 + gi;
        const int zp = g >> 3, yp = g & 7;
        const int oz = z0 + zp, oy = y0 + yp;
        if (oz >= E2 || oy >= E2) continue;          // wave-uniform
        f32x4 acc = {0.f, 0.f, 0.f, 0.f};
#pragma unroll
        for (int t = 0; t < 14; ++t) {
            const int tap0 = 2 * t;
            const int tap1 = (2 * t + 1 > 26) ? 26 : 2 * t + 1;   // tap27: B==0
            const int kz0 = tap0 / 9, ky0 = (tap0 / 3) % 3, kx0 = tap0 % 3;
            const int kz1 = tap1 / 9, ky1 = (tap1 / 3) % 3, kx1 = tap1 % 3;
            const int r0 = ((zp + kz0) * 10 + (yp + ky0)) * 640;
            const int r1 = ((zp + kz1) * 10 + (yp + ky1)) * 640;
            const int xi = (lane & 15) + (s ? kx1 : kx0);
            const int off = (s ? r1 : r0) + swz(xi, h);
            const short8 a = *(const short8*)(sX1 + off);
            acc = __builtin_amdgcn_mfma_f32_16x16x32_bf16(a, B2[t], acc, 0, 0, 0);
        }
        // x2 bf16 record write: col 0..4 = data, 5..7 = exact zeros (B2 zero -> acc==0)
        if (col < 8) {
#pragma unroll
            for (int jj = 0; jj < 4; ++jj) {
                const int ox = x0 + q4 * 4 + jj;
                if (ox < E2)
                    x2s[(size_t)(((b * E2 + oz) * E2 + oy) * E2 + ox) * 8 + col] =
                        (short)f2bf(acc[jj]);
            }
        }
    }
}

// ---------------- stage 3: conv3 + bias + relu via MFMA ----------------
// Block: 256 threads (4 waves). Output tile (z8, y8, x16). x2 (bf16 8-ch records) halo
// 10x10x18 staged in LDS via one b128 load + one b128 write per position.
__global__ __launch_bounds__(256, 4) void conv3_k(const short* __restrict__ x2s,
                                                  const float* __restrict__ W3f,
                                                  const float* __restrict__ b3f,
                                                  float* __restrict__ out) {
    __shared__ __align__(16) char sX2[38400];   // 100 rows * 384B

    const int tid = threadIdx.x;
    int blk = blockIdx.x;
    const int xt  = blk & 7;  blk >>= 3;
    const int tyt = blk & 15; blk >>= 4;
    const int tzt = blk & 15; blk >>= 4;
    const int b   = blk;
    const int z0 = tzt * 8, y0 = tyt * 8, x0 = xt * 16;

    // ---- stage x2 halo tile: 10z * 10y * 18x positions, one 16B record each
#pragma unroll 1
    for (int p = tid; p < 1800; p += 256) {
        const int xp = p % 18; int t2 = p / 18;
        const int yp = t2 % 10; const int zp = t2 / 10;
        const int iz = min(z0 + zp, E2 - 1);
        const int iy = min(y0 + yp, E2 - 1);
        const int ix = min(x0 + xp, E2 - 1);
        const short8 rec = *(const short8*)(x2s + (size_t)(((b * E2 + iz) * E2 + iy) * E2 + ix) * 8);
        *(short8*)(sX2 + r3off(zp * 10 + yp, xp)) = rec;
    }

    // ---- conv3 B-fragments: k' = tap*8+ci (27 taps + 1 pad), col = out-ch (3 used)
    const int lane = tid & 63;
    const int col  = lane & 15;
    const int q4   = lane >> 4;
    short8 B3[7];
#pragma unroll
    for (int t = 0; t < 7; ++t) {
        const int tap = 4 * t + q4;          // k' = 32t + q4*8 + j -> tap = 4t+q4, ci = j
#pragma unroll
        for (int j = 0; j < 8; ++j) {
            float v = 0.f;
            if (tap < 27 && j < 5 && col < 3) v = W3f[(tap * 5 + j) * 3 + col];
            B3[t][j] = (short)f2bf(v);
        }
    }
    const float bias = (col < 3) ? b3f[col] : 0.f;
    __syncthreads();

    // ---- MFMA: groups g = (z'<<3)|y', 64 groups / 4 waves = 16 per wave
    const int wv = tid >> 6;
#pragma unroll 1
    for (int gi = 0; gi < 16; ++gi) {
        const int g = wv * 16 + gi;
        const int zp = g >> 3, yp = g & 7;
        const int oz = z0 + zp, oy = y0 + yp;
        if (oz >= E3 || oy >= E3) continue;          // wave-uniform
        f32x4 acc = {0.f, 0.f, 0.f, 0.f};
#pragma unroll
        for (int t = 0; t < 7; ++t) {
            const int tap = (4 * t + q4 > 26) ? 26 : 4 * t + q4;   // tap27: B==0
            const int kz = tap / 9, ky = (tap / 3) % 3, kx = tap % 3;
            const int row = (zp + kz) * 10 + (yp + ky);
            const int xi = (lane & 15) + kx;
            const short8 a = *(const short8*)(sX2 + r3off(row, xi));
            acc = __builtin_amdgcn_mfma_f32_16x16x32_bf16(a, B3[t], acc, 0, 0, 0);
        }
        if (col < 3) {
#pragma unroll
            for (int jj = 0; jj < 4; ++jj) {
                const int ox = x0 + q4 * 4 + jj;
                if (ox < E3)
                    out[(size_t)(((b * E3 + oz) * E3 + oy) * E3 + ox) * 3 + col] =
                        fmaxf(acc[jj] + bias, 0.f);
            }
        }
    }
}

extern "C" void kernel_launch(void* const* d_in, const int* in_sizes, int n_in,
                              void* d_out, int out_size, void* d_ws, size_t ws_size,
                              hipStream_t stream) {
    const int*   coords = (const int*)d_in[0];
    const float* voxels = (const float*)d_in[1];
    const float* W1     = (const float*)d_in[2];
    const float* W2     = (const float*)d_in[3];
    const float* W3     = (const float*)d_in[4];
    const float* b3     = (const float*)d_in[5];
    float* out = (float*)d_out;

    const int N = in_sizes[0] / 4;  // 100000

    // workspace: dense 4-ch padded fp32 (67.1 MB) + x2 bf16 8-ch (62.5 MB) = 129.6 MB
    char* ws = (char*)d_ws;
    const size_t dense_elems = (size_t)2 * DGRID * DGRID * DGRID * 4;
    const size_t dense_bytes = dense_elems * sizeof(float);
    float* dense = (float*)ws;
    short* x2s   = (short*)(ws + dense_bytes);

    const int n4 = (int)(dense_elems / 4);
    zero_k<<<(n4 + 255) / 256, 256, 0, stream>>>((float4*)dense, n4);

    scatter_k<<<(N * 3 + 255) / 256, 256, 0, stream>>>(coords, voxels, dense, N);

    // conv12: B * z-tiles(16 of 8) * y-tiles(16 of 8) * x-tiles(8 of 16)
    const int nblk12 = 2 * 16 * 16 * 8;
    conv12_k<<<nblk12, 256, 0, stream>>>(dense, W1, W2, x2s);

    // conv3: B * z-tiles(16 of 8) * y-tiles(16 of 8) * x-tiles(8 of 16)
    const int nblk3 = 2 * 16 * 16 * 8;
    conv3_k<<<nblk3, 256, 0, stream>>>(x2s, W3, b3, out);
}

// Round 12
// 369.870 us; speedup vs baseline: 1.1062x; 1.1062x over previous
//
#include <hip/hip_runtime.h>
#include <hip/hip_bf16.h>

#define DGRID 128
#define E1 127
#define E2 125
#define E3 123

typedef __attribute__((ext_vector_type(8))) short short8;
typedef __attribute__((ext_vector_type(4))) float f32x4;

static __device__ __forceinline__ unsigned short f2bf(float f) {
    union { __hip_bfloat16 h; unsigned short u; } cv;
    cv.h = __float2bfloat16(f);
    return cv.u;
}

// conv12 x1-row swizzle: row = 20 slots * 32B = 640B, XOR bits[4:6] by (x>>2).
static __device__ __forceinline__ int swz(int x, int h) {
    int off = x * 32 + h * 16;
    return off ^ (((x >> 2) & 7) << 4);
}

// conv3 x2-record offset: row padded to 24 slots * 16B = 384B; XOR bits[4:6] by (row&7).
static __device__ __forceinline__ int r3off(int row, int x) {
    return row * 384 + ((x * 16) ^ ((row & 7) << 4));
}

// ---------------- stage 0: zero dense grid (4-ch padded) ----------------
__global__ __launch_bounds__(256) void zero_k(float4* __restrict__ p, int n4) {
    int i = blockIdx.x * 256 + threadIdx.x;
    if (i < n4) p[i] = make_float4(0.f, 0.f, 0.f, 0.f);
}

// ---------------- stage 1: scatter voxels into dense grid ----------------
__global__ __launch_bounds__(256) void scatter_k(const int* __restrict__ coords,
                                                 const float* __restrict__ voxels,
                                                 float* __restrict__ dense, int N) {
    int i = blockIdx.x * blockDim.x + threadIdx.x;
    if (i >= N * 3) return;
    int n = i / 3, c = i - n * 3;
    int b = coords[n * 4 + 0];
    int z = coords[n * 4 + 1];
    int y = coords[n * 4 + 2];
    int x = coords[n * 4 + 3];
    int idx = (((b * DGRID + z) * DGRID + y) * DGRID + x) * 4 + c;   // 4-ch padded
    atomicAdd(&dense[idx], voxels[n * 3 + c]);
}

// ---------------- stage 2: fused conv1 (fp32 VALU, r6 structure) + conv2 (bf16 MFMA) ----------------
// Block: 256 threads (4 waves). Output tile (z8, y8, x16) of x2.
// Phase 1 (round-6 proven form): 4 positions/thread, per-tap w[27] uniform loads,
//          scalar dense reads; x1 tile [10z][10y][18x] fp32 -> bf16 swizzled LDS.
// Phase 2: implicit GEMM, 14 x mfma_16x16x32_bf16 per 16 outputs; weights in 56 VGPRs.
// Epilogue: x2 written as bf16 8-ch records (16B); cols 5..7 exact 0 (B-frag zero).
__global__ __launch_bounds__(256, 2) void conv12_k(const float* __restrict__ dense,
                                                   const float* __restrict__ W1f,
                                                   const float* __restrict__ W2f,
                                                   short* __restrict__ x2s) {
    __shared__ __align__(16) char sX1[64000];   // 10z * 10y rows * 640B

    const int tid = threadIdx.x;
    int blk = blockIdx.x;
    const int xt  = blk & 7;  blk >>= 3;
    const int tyt = blk & 15; blk >>= 4;
    const int tzt = blk & 15; blk >>= 4;
    const int b   = blk;
    const int z0 = tzt * 8, y0 = tyt * 8, x0 = xt * 16;

    // ---- phase 1: conv1 (round-6 structure), 4 positions per thread-rep
#pragma unroll 1
    for (int rep = 0; rep < 2; ++rep) {
        const int pbase = rep * 1024 + tid * 4;
        if (pbase >= 1800) continue;
        int xs[4], ys[4], zs[4];
#pragma unroll
        for (int q = 0; q < 4; ++q) {
            int i = min(pbase + q, 1799);
            xs[q] = i % 18; int t2 = i / 18; ys[q] = t2 % 10; zs[q] = t2 / 10;
        }
        float acc[4][9];
#pragma unroll
        for (int q = 0; q < 4; ++q)
#pragma unroll
            for (int o = 0; o < 9; ++o) acc[q][o] = 0.f;

#pragma unroll 1
        for (int tap = 0; tap < 8; ++tap) {
            const int kz = tap >> 2, ky = (tap >> 1) & 1, kx = tap & 1;
            float w[27];                       // uniform -> scalar loads
#pragma unroll
            for (int i = 0; i < 27; ++i) w[i] = W1f[tap * 27 + i];
#pragma unroll
            for (int q = 0; q < 4; ++q) {
                const int dz = min(z0 + zs[q] + kz, DGRID - 1);
                const int dy = min(y0 + ys[q] + ky, DGRID - 1);
                const int dx = min(x0 + xs[q] + kx, DGRID - 1);
                const float* dp = dense + (size_t)(((b * DGRID + dz) * DGRID + dy) * DGRID + dx) * 4;
                const float v0 = dp[0], v1 = dp[1], v2 = dp[2];
#pragma unroll
                for (int o = 0; o < 9; ++o)
                    acc[q][o] += v0 * w[o] + v1 * w[9 + o] + v2 * w[18 + o];
            }
        }
#pragma unroll
        for (int q = 0; q < 4; ++q) {
            if (pbase + q < 1800) {
                const int R = (zs[q] * 10 + ys[q]) * 640;
                short8 lo, hi;
#pragma unroll
                for (int o = 0; o < 8; ++o) lo[o] = (short)f2bf(acc[q][o]);
                hi[0] = (short)f2bf(acc[q][8]);
#pragma unroll
                for (int o = 1; o < 8; ++o) hi[o] = 0;
                *(short8*)(sX1 + R + swz(xs[q], 0)) = lo;
                *(short8*)(sX1 + R + swz(xs[q], 1)) = hi;
            }
        }
    }

    // ---- conv2 B-fragments: k' = tap*16+ci, col = out-ch; lane: col=lane&15, k'=32t+(lane>>4)*8+j
    const int lane = tid & 63;
    const int col  = lane & 15;
    const int q4   = lane >> 4;          // 0..3
    short8 B2[14];
#pragma unroll
    for (int t = 0; t < 14; ++t) {
#pragma unroll
        for (int j = 0; j < 8; ++j) {
            const int kp = t * 32 + q4 * 8 + j;
            const int tap = kp >> 4, ci = kp & 15;
            float v = 0.f;
            if (tap < 27 && ci < 9 && col < 5) v = W2f[(tap * 9 + ci) * 5 + col];
            B2[t][j] = (short)f2bf(v);
        }
    }
    __syncthreads();

    // ---- phase 2: conv2 via MFMA. Groups g = (z'<<3)|y', 64 groups / 4 waves.
    const int wv = tid >> 6;
    const int s  = q4 >> 1;              // tap-parity selector
    const int h  = q4 & 1;               // 16B-half (ci 0-7 / 8-15)
#pragma unroll 1
    for (int gi = 0; gi < 16; ++gi) {
        const int g = wv * 16 + gi;
        const int zp = g >> 3, yp = g & 7;
        const int oz = z0 + zp, oy = y0 + yp;
        if (oz >= E2 || oy >= E2) continue;          // wave-uniform
        f32x4 acc = {0.f, 0.f, 0.f, 0.f};
#pragma unroll
        for (int t = 0; t < 14; ++t) {
            const int tap0 = 2 * t;
            const int tap1 = (2 * t + 1 > 26) ? 26 : 2 * t + 1;   // tap27: B==0
            const int kz0 = tap0 / 9, ky0 = (tap0 / 3) % 3, kx0 = tap0 % 3;
            const int kz1 = tap1 / 9, ky1 = (tap1 / 3) % 3, kx1 = tap1 % 3;
            const int r0 = ((zp + kz0) * 10 + (yp + ky0)) * 640;
            const int r1 = ((zp + kz1) * 10 + (yp + ky1)) * 640;
            const int xi = (lane & 15) + (s ? kx1 : kx0);
            const int off = (s ? r1 : r0) + swz(xi, h);
            const short8 a = *(const short8*)(sX1 + off);
            acc = __builtin_amdgcn_mfma_f32_16x16x32_bf16(a, B2[t], acc, 0, 0, 0);
        }
        // x2 bf16 record write: col 0..4 = data, 5..7 = exact zeros (B2 zero -> acc==0)
        if (col < 8) {
#pragma unroll
            for (int jj = 0; jj < 4; ++jj) {
                const int ox = x0 + q4 * 4 + jj;
                if (ox < E2)
                    x2s[(size_t)(((b * E2 + oz) * E2 + oy) * E2 + ox) * 8 + col] =
                        (short)f2bf(acc[jj]);
            }
        }
    }
}

// ---------------- stage 3: conv3 + bias + relu via MFMA ----------------
// Block: 256 threads (4 waves). Output tile (z8, y8, x16). x2 (bf16 8-ch records) halo
// 10x10x18 staged in LDS via one b128 load + one b128 write per position.
__global__ __launch_bounds__(256, 4) void conv3_k(const short* __restrict__ x2s,
                                                  const float* __restrict__ W3f,
                                                  const float* __restrict__ b3f,
                                                  float* __restrict__ out) {
    __shared__ __align__(16) char sX2[38400];   // 100 rows * 384B

    const int tid = threadIdx.x;
    int blk = blockIdx.x;
    const int xt  = blk & 7;  blk >>= 3;
    const int tyt = blk & 15; blk >>= 4;
    const int tzt = blk & 15; blk >>= 4;
    const int b   = blk;
    const int z0 = tzt * 8, y0 = tyt * 8, x0 = xt * 16;

    // ---- stage x2 halo tile: 10z * 10y * 18x positions, one 16B record each
#pragma unroll 1
    for (int p = tid; p < 1800; p += 256) {
        const int xp = p % 18; int t2 = p / 18;
        const int yp = t2 % 10; const int zp = t2 / 10;
        const int iz = min(z0 + zp, E2 - 1);
        const int iy = min(y0 + yp, E2 - 1);
        const int ix = min(x0 + xp, E2 - 1);
        const short8 rec = *(const short8*)(x2s + (size_t)(((b * E2 + iz) * E2 + iy) * E2 + ix) * 8);
        *(short8*)(sX2 + r3off(zp * 10 + yp, xp)) = rec;
    }

    // ---- conv3 B-fragments: k' = tap*8+ci (27 taps + 1 pad), col = out-ch (3 used)
    const int lane = tid & 63;
    const int col  = lane & 15;
    const int q4   = lane >> 4;
    short8 B3[7];
#pragma unroll
    for (int t = 0; t < 7; ++t) {
        const int tap = 4 * t + q4;          // k' = 32t + q4*8 + j -> tap = 4t+q4, ci = j
#pragma unroll
        for (int j = 0; j < 8; ++j) {
            float v = 0.f;
            if (tap < 27 && j < 5 && col < 3) v = W3f[(tap * 5 + j) * 3 + col];
            B3[t][j] = (short)f2bf(v);
        }
    }
    const float bias = (col < 3) ? b3f[col] : 0.f;
    __syncthreads();

    // ---- MFMA: groups g = (z'<<3)|y', 64 groups / 4 waves = 16 per wave
    const int wv = tid >> 6;
#pragma unroll 1
    for (int gi = 0; gi < 16; ++gi) {
        const int g = wv * 16 + gi;
        const int zp = g >> 3, yp = g & 7;
        const int oz = z0 + zp, oy = y0 + yp;
        if (oz >= E3 || oy >= E3) continue;          // wave-uniform
        f32x4 acc = {0.f, 0.f, 0.f, 0.f};
#pragma unroll
        for (int t = 0; t < 7; ++t) {
            const int tap = (4 * t + q4 > 26) ? 26 : 4 * t + q4;   // tap27: B==0
            const int kz = tap / 9, ky = (tap / 3) % 3, kx = tap % 3;
            const int row = (zp + kz) * 10 + (yp + ky);
            const int xi = (lane & 15) + kx;
            const short8 a = *(const short8*)(sX2 + r3off(row, xi));
            acc = __builtin_amdgcn_mfma_f32_16x16x32_bf16(a, B3[t], acc, 0, 0, 0);
        }
        if (col < 3) {
#pragma unroll
            for (int jj = 0; jj < 4; ++jj) {
                const int ox = x0 + q4 * 4 + jj;
                if (ox < E3)
                    out[(size_t)(((b * E3 + oz) * E3 + oy) * E3 + ox) * 3 + col] =
                        fmaxf(acc[jj] + bias, 0.f);
            }
        }
    }
}

extern "C" void kernel_launch(void* const* d_in, const int* in_sizes, int n_in,
                              void* d_out, int out_size, void* d_ws, size_t ws_size,
                              hipStream_t stream) {
    const int*   coords = (const int*)d_in[0];
    const float* voxels = (const float*)d_in[1];
    const float* W1     = (const float*)d_in[2];
    const float* W2     = (const float*)d_in[3];
    const float* W3     = (const float*)d_in[4];
    const float* b3     = (const float*)d_in[5];
    float* out = (float*)d_out;

    const int N = in_sizes[0] / 4;  // 100000

    // workspace: dense 4-ch padded fp32 (67.1 MB) + x2 bf16 8-ch (62.5 MB) = 129.6 MB
    char* ws = (char*)d_ws;
    const size_t dense_elems = (size_t)2 * DGRID * DGRID * DGRID * 4;
    const size_t dense_bytes = dense_elems * sizeof(float);
    float* dense = (float*)ws;
    short* x2s   = (short*)(ws + dense_bytes);

    const int n4 = (int)(dense_elems / 4);
    zero_k<<<(n4 + 255) / 256, 256, 0, stream>>>((float4*)dense, n4);

    scatter_k<<<(N * 3 + 255) / 256, 256, 0, stream>>>(coords, voxels, dense, N);

    // conv12: B * z-tiles(16 of 8) * y-tiles(16 of 8) * x-tiles(8 of 16)
    const int nblk12 = 2 * 16 * 16 * 8;
    conv12_k<<<nblk12, 256, 0, stream>>>(dense, W1, W2, x2s);

    // conv3: B * z-tiles(16 of 8) * y-tiles(16 of 8) * x-tiles(8 of 16)
    const int nblk3 = 2 * 16 * 16 * 8;
    conv3_k<<<nblk3, 256, 0, stream>>>(x2s, W3, b3, out);
}

// Round 13
// 229.781 us; speedup vs baseline: 1.7807x; 1.6097x over previous
//
#include <hip/hip_runtime.h>
#include <hip/hip_bf16.h>

#define DGRID 128
#define E1 127
#define E2 125
#define E3 123

typedef __attribute__((ext_vector_type(8))) short short8;
typedef __attribute__((ext_vector_type(4))) float f32x4;
typedef __attribute__((ext_vector_type(4))) unsigned int u32x4;

static __device__ __forceinline__ unsigned short f2bf(float f) {
    union { __hip_bfloat16 h; unsigned short u; } cv;
    cv.h = __float2bfloat16(f);
    return cv.u;
}

// conv3 x2-record offset: row padded to 24 slots * 16B = 384B; XOR bits[4:6] by (row&7).
static __device__ __forceinline__ int r3off(int row, int x) {
    return row * 384 + ((x * 16) ^ ((row & 7) << 4));
}

// ---------------- stage 0: zero dense grid (4-ch padded) ----------------
__global__ __launch_bounds__(256) void zero_k(float4* __restrict__ p, int n4) {
    int i = blockIdx.x * 256 + threadIdx.x;
    if (i < n4) p[i] = make_float4(0.f, 0.f, 0.f, 0.f);
}

// ---------------- stage 1: scatter voxels into dense grid ----------------
__global__ __launch_bounds__(256) void scatter_k(const int* __restrict__ coords,
                                                 const float* __restrict__ voxels,
                                                 float* __restrict__ dense, int N) {
    int i = blockIdx.x * blockDim.x + threadIdx.x;
    if (i >= N * 3) return;
    int n = i / 3, c = i - n * 3;
    int b = coords[n * 4 + 0];
    int z = coords[n * 4 + 1];
    int y = coords[n * 4 + 2];
    int x = coords[n * 4 + 3];
    int idx = (((b * DGRID + z) * DGRID + y) * DGRID + x) * 4 + c;   // 4-ch padded
    atomicAdd(&dense[idx], voxels[n * 3 + c]);
}

// ---------------- stage 1b: compose W12 = conv1 o conv2 (4x4x4 x 3ci x 5co, fp32) ----------------
// W12[KZ][KY][KX][ci][co] = sum_{k1+k2=K} sum_m W1[k1][ci][m] * W2[k2][m][co]
__global__ __launch_bounds__(256) void wcomp_k(const float* __restrict__ W1f,
                                               const float* __restrict__ W2f,
                                               float* __restrict__ W12) {
    for (int e = threadIdx.x; e < 960; e += 256) {
        const int tap = e / 15, r = e % 15;
        const int ci = r / 5, co = r % 5;
        const int KZ = tap >> 4, KY = (tap >> 2) & 3, KX = tap & 3;
        float acc = 0.f;
#pragma unroll
        for (int k1z = 0; k1z < 2; ++k1z) {
            const int k2z = KZ - k1z;
            if (k2z < 0 || k2z > 2) continue;
#pragma unroll
            for (int k1y = 0; k1y < 2; ++k1y) {
                const int k2y = KY - k1y;
                if (k2y < 0 || k2y > 2) continue;
#pragma unroll
                for (int k1x = 0; k1x < 2; ++k1x) {
                    const int k2x = KX - k1x;
                    if (k2x < 0 || k2x > 2) continue;
                    const float* w1 = W1f + ((k1z * 2 + k1y) * 2 + k1x) * 27 + ci * 9;
                    const float* w2 = W2f + ((k2z * 3 + k2y) * 3 + k2x) * 45 + co;
#pragma unroll
                    for (int m = 0; m < 9; ++m) acc += w1[m] * w2[m * 5];
                }
            }
        }
        W12[tap * 15 + r] = acc;
    }
}

// ---------------- stage 2: composed conv1+conv2 as ONE direct 4^3 conv (bf16 MFMA) ----------------
// Block: 256 threads (4 waves). Output tile (z8, y8, x16) of x2.
// Dense halo 11x11x19 staged as bf16 4-ch 8B records in LDS (19.4 KB).
// K = 64 taps x 4 ch = 256 -> 8 x mfma_16x16x32_bf16 per 16 outputs.
// k' = 32t + 8*q4 + j  <->  tap = k'>>2 = 8t + 2*q4 + (j>>2), ci = k'&3 = j&3.
// A (data): row = lane&15 = x-position; fragment = records x+kx0, x+kx0+1 (two uint2 reads).
// B (weights): col = lane&15 = out-ch; gathered from W12. Epilogue identical to proven conv2.
__global__ __launch_bounds__(256, 4) void conv12_k(const float* __restrict__ dense,
                                                   const float* __restrict__ W12,
                                                   short* __restrict__ x2s) {
    __shared__ __align__(16) char sDD[19360];   // 121 rows (z*11+y) * 20 slots * 8B

    const int tid = threadIdx.x;
    int blk = blockIdx.x;
    const int xt  = blk & 7;  blk >>= 3;
    const int tyt = blk & 15; blk >>= 4;
    const int tzt = blk & 15; blk >>= 4;
    const int b   = blk;
    const int z0 = tzt * 8, y0 = tyt * 8, x0 = xt * 16;

    const int lane = tid & 63;
    const int col  = lane & 15;
    const int q4   = lane >> 4;          // 0..3
    const int wv   = tid >> 6;

    // ---- B-fragments from W12: tap = 8t + 2*q4 + (j>>2), ci = j&3
    short8 B12[8];
#pragma unroll
    for (int t = 0; t < 8; ++t) {
#pragma unroll
        for (int j = 0; j < 8; ++j) {
            const int tap = 8 * t + 2 * q4 + (j >> 2);
            const int ci  = j & 3;
            float v = (ci < 3 && col < 5) ? W12[tap * 15 + ci * 5 + col] : 0.f;
            B12[t][j] = (short)f2bf(v);
        }
    }

    // ---- per-lane A-read offsets per t (row/col-independent part)
    int offt[8];
#pragma unroll
    for (int t = 0; t < 8; ++t) {
        const int T0 = 8 * t + 2 * q4;
        const int kz = T0 >> 4, ky = (T0 >> 2) & 3, kx0 = T0 & 3;   // kx0 in {0,2}
        offt[t] = (kz * 11 + ky) * 160 + kx0 * 8;
    }

    // ---- stage dense halo: 11z * 11y * 19x records (float4 -> bf16x4, 8B)
#pragma unroll 1
    for (int p = tid; p < 2299; p += 256) {
        const int xp = p % 19; int t2 = p / 19;
        const int yp = t2 % 11; const int zp = t2 / 11;
        const int gz = min(z0 + zp, DGRID - 1);
        const int gy = min(y0 + yp, DGRID - 1);
        const int gx = min(x0 + xp, DGRID - 1);
        const float4 v = *(const float4*)(dense +
            (size_t)(((b * DGRID + gz) * DGRID + gy) * DGRID + gx) * 4);
        const unsigned lo = (unsigned)f2bf(v.x) | ((unsigned)f2bf(v.y) << 16);
        const unsigned hi = (unsigned)f2bf(v.z) | ((unsigned)f2bf(v.w) << 16);
        *(uint2*)(sDD + (zp * 11 + yp) * 160 + xp * 8) = make_uint2(lo, hi);
    }
    __syncthreads();

    // ---- MFMA: 64 groups (z8 x y8) / 4 waves = 16 per wave; 8 mfma per group
#pragma unroll 1
    for (int gi = 0; gi < 16; ++gi) {
        const int g = wv * 16 + gi;
        const int zp = g >> 3, yp = g & 7;
        const int oz = z0 + zp, oy = y0 + yp;
        if (oz >= E2 || oy >= E2) continue;          // wave-uniform
        const int baseg = (zp * 11 + yp) * 160 + col * 8;
        f32x4 acc = {0.f, 0.f, 0.f, 0.f};
#pragma unroll
        for (int t = 0; t < 8; ++t) {
            const char* p = sDD + baseg + offt[t];
            const uint2 ra = *(const uint2*)(p);        // tap T0: ci 0..3
            const uint2 rb = *(const uint2*)(p + 8);    // tap T0+1: ci 0..3
            union { u32x4 u; short8 s; } av;
            av.u[0] = ra.x; av.u[1] = ra.y; av.u[2] = rb.x; av.u[3] = rb.y;
            acc = __builtin_amdgcn_mfma_f32_16x16x32_bf16(av.s, B12[t], acc, 0, 0, 0);
        }
        // x2 bf16 record write: col 0..4 = data, 5..7 exact zeros (B12 zero -> acc==0)
        if (col < 8) {
#pragma unroll
            for (int jj = 0; jj < 4; ++jj) {
                const int ox = x0 + q4 * 4 + jj;
                if (ox < E2)
                    x2s[(size_t)(((b * E2 + oz) * E2 + oy) * E2 + ox) * 8 + col] =
                        (short)f2bf(acc[jj]);
            }
        }
    }
}

// ---------------- stage 3: conv3 + bias + relu via MFMA (unchanged, proven) ----------------
__global__ __launch_bounds__(256, 4) void conv3_k(const short* __restrict__ x2s,
                                                  const float* __restrict__ W3f,
                                                  const float* __restrict__ b3f,
                                                  float* __restrict__ out) {
    __shared__ __align__(16) char sX2[38400];   // 100 rows * 384B

    const int tid = threadIdx.x;
    int blk = blockIdx.x;
    const int xt  = blk & 7;  blk >>= 3;
    const int tyt = blk & 15; blk >>= 4;
    const int tzt = blk & 15; blk >>= 4;
    const int b   = blk;
    const int z0 = tzt * 8, y0 = tyt * 8, x0 = xt * 16;

    // ---- stage x2 halo tile: 10z * 10y * 18x positions, one 16B record each
#pragma unroll 1
    for (int p = tid; p < 1800; p += 256) {
        const int xp = p % 18; int t2 = p / 18;
        const int yp = t2 % 10; const int zp = t2 / 10;
        const int iz = min(z0 + zp, E2 - 1);
        const int iy = min(y0 + yp, E2 - 1);
        const int ix = min(x0 + xp, E2 - 1);
        const short8 rec = *(const short8*)(x2s + (size_t)(((b * E2 + iz) * E2 + iy) * E2 + ix) * 8);
        *(short8*)(sX2 + r3off(zp * 10 + yp, xp)) = rec;
    }

    // ---- conv3 B-fragments: k' = tap*8+ci (27 taps + 1 pad), col = out-ch (3 used)
    const int lane = tid & 63;
    const int col  = lane & 15;
    const int q4   = lane >> 4;
    short8 B3[7];
#pragma unroll
    for (int t = 0; t < 7; ++t) {
        const int tap = 4 * t + q4;          // k' = 32t + q4*8 + j -> tap = 4t+q4, ci = j
#pragma unroll
        for (int j = 0; j < 8; ++j) {
            float v = 0.f;
            if (tap < 27 && j < 5 && col < 3) v = W3f[(tap * 5 + j) * 3 + col];
            B3[t][j] = (short)f2bf(v);
        }
    }
    const float bias = (col < 3) ? b3f[col] : 0.f;
    __syncthreads();

    // ---- MFMA: groups g = (z'<<3)|y', 64 groups / 4 waves = 16 per wave
    const int wv = tid >> 6;
#pragma unroll 1
    for (int gi = 0; gi < 16; ++gi) {
        const int g = wv * 16 + gi;
        const int zp = g >> 3, yp = g & 7;
        const int oz = z0 + zp, oy = y0 + yp;
        if (oz >= E3 || oy >= E3) continue;          // wave-uniform
        f32x4 acc = {0.f, 0.f, 0.f, 0.f};
#pragma unroll
        for (int t = 0; t < 7; ++t) {
            const int tap = (4 * t + q4 > 26) ? 26 : 4 * t + q4;   // tap27: B==0
            const int kz = tap / 9, ky = (tap / 3) % 3, kx = tap % 3;
            const int row = (zp + kz) * 10 + (yp + ky);
            const int xi = (lane & 15) + kx;
            const short8 a = *(const short8*)(sX2 + r3off(row, xi));
            acc = __builtin_amdgcn_mfma_f32_16x16x32_bf16(a, B3[t], acc, 0, 0, 0);
        }
        if (col < 3) {
#pragma unroll
            for (int jj = 0; jj < 4; ++jj) {
                const int ox = x0 + q4 * 4 + jj;
                if (ox < E3)
                    out[(size_t)(((b * E3 + oz) * E3 + oy) * E3 + ox) * 3 + col] =
                        fmaxf(acc[jj] + bias, 0.f);
            }
        }
    }
}

extern "C" void kernel_launch(void* const* d_in, const int* in_sizes, int n_in,
                              void* d_out, int out_size, void* d_ws, size_t ws_size,
                              hipStream_t stream) {
    const int*   coords = (const int*)d_in[0];
    const float* voxels = (const float*)d_in[1];
    const float* W1     = (const float*)d_in[2];
    const float* W2     = (const float*)d_in[3];
    const float* W3     = (const float*)d_in[4];
    const float* b3     = (const float*)d_in[5];
    float* out = (float*)d_out;

    const int N = in_sizes[0] / 4;  // 100000

    // workspace: dense 4-ch fp32 (67.1 MB) + x2 bf16 8-ch (62.5 MB) + W12 (3.84 KB)
    char* ws = (char*)d_ws;
    const size_t dense_elems = (size_t)2 * DGRID * DGRID * DGRID * 4;
    const size_t dense_bytes = dense_elems * sizeof(float);
    const size_t x2_bytes    = (size_t)2 * E2 * E2 * E2 * 8 * sizeof(short);
    float* dense = (float*)ws;
    short* x2s   = (short*)(ws + dense_bytes);
    float* W12   = (float*)(ws + dense_bytes + x2_bytes);

    const int n4 = (int)(dense_elems / 4);
    zero_k<<<(n4 + 255) / 256, 256, 0, stream>>>((float4*)dense, n4);

    scatter_k<<<(N * 3 + 255) / 256, 256, 0, stream>>>(coords, voxels, dense, N);

    wcomp_k<<<1, 256, 0, stream>>>(W1, W2, W12);

    // conv12: B * z-tiles(16 of 8) * y-tiles(16 of 8) * x-tiles(8 of 16)
    const int nblk12 = 2 * 16 * 16 * 8;
    conv12_k<<<nblk12, 256, 0, stream>>>(dense, W12, x2s);

    // conv3: B * z-tiles(16 of 8) * y-tiles(16 of 8) * x-tiles(8 of 16)
    const int nblk3 = 2 * 16 * 16 * 8;
    conv3_k<<<nblk3, 256, 0, stream>>>(x2s, W3, b3, out);
}